// Round 4
// baseline (1581889.355 us; speedup 1.0000x reference)
//
#include <hip/hip_runtime.h>

typedef unsigned int u32;
typedef unsigned short u16;
typedef unsigned long long u64;
typedef __attribute__((ext_vector_type(4))) float f32x4;
typedef __attribute__((ext_vector_type(8))) short short8;

#define S_LEN 4096
#define EDIM 1024
#define HDIM 512
#define G4 2048
#define NLAY 3
#define NTAG 5
#define NEGV -10000.0f
#define NGRP 16
#define CHUNK 256
#define WARM 64
#define RING_SLOTS 392
#define RING_L (RING_SLOTS*NLAY)
#define FSTRIDE 16              // u32s per flag (64B line each)
#define NFLAG_LINES (NLAY*2*NGRP*8)
#define NREG_LINES (NLAY*8)
#define NFLAGS_TOT ((NFLAG_LINES + NREG_LINES)*FSTRIDE)

__device__ __forceinline__ u16 tobf(float x){
  u32 u = __float_as_uint(x);
  u32 r = (u + 0x7FFFu + ((u >> 16) & 1u)) >> 16;
  return (u16)r;
}
__device__ __forceinline__ float frombf(u16 h){ return __uint_as_float(((u32)h) << 16); }
__device__ __forceinline__ float sigmf(float x){ return 1.0f / (1.0f + __expf(-x)); }
__device__ __forceinline__ float tanh_fast(float x){
  float e = __expf(-2.0f * fabsf(x));
  float t = (1.0f - e) / (1.0f + e);
  return copysignf(t, x);
}

// ---------------- init: zero barrier flags + registration counters ----------------
__global__ void init_k(u32* flags){
  int i = blockIdx.x*256 + threadIdx.x;
  if (i < NFLAGS_TOT) flags[i] = 0u;
}

// ---------------- embedding gather -> bf16 ----------------
__global__ void gather_k(const int* __restrict__ sent, const float* __restrict__ emb, u16* __restrict__ xa){
  int idx = blockIdx.x*256 + threadIdx.x;      // S*E/4 threads
  int p = idx >> 8;
  int k = (idx & 255) << 2;
  int tok = sent[p];
  f32x4 v = *(const f32x4*)(emb + (size_t)tok*EDIM + k);
  u16* o = xa + (size_t)p*EDIM + k;
  o[0]=tobf(v.x); o[1]=tobf(v.y); o[2]=tobf(v.z); o[3]=tobf(v.w);
}

// ---------------- per-layer prep: cast w_ih, repack w_hh MFMA A-frags, bias ----------------
// wfrag flat layout: ((((dir*8+m)*16 + t)*16 + kk)*64 + lane)*8 + e
//   tile t: gate g = t>>2, subband = t&3; row = g*512 + m*64 + (t&3)*16 + (lane&15)
//   k = kk*32 + (lane>>4)*8 + e   (full K=512 per tile, kk in [0,16))
__global__ void prep_k(int lay, const float* __restrict__ w_ih, const float* __restrict__ w_hh,
                       const float* __restrict__ b_ih, const float* __restrict__ b_hh,
                       u16* __restrict__ wihb, u16* __restrict__ wfrag, float* __restrict__ bias){
  int gi = blockIdx.x*256 + threadIdx.x;
  const int R0 = 2*G4*EDIM;   // 4194304
  const int R1 = 2*G4*HDIM;   // 2097152
  if (gi < R0){
    wihb[gi] = tobf(w_ih[(size_t)lay*R0 + gi]);
  } else if (gi < R0 + R1){
    int a = gi - R0;
    int e = a & 7, lane = (a>>3)&63, kk = (a>>9)&15, t = (a>>13)&15, m = (a>>17)&7, dir = (a>>20)&1;
    int row = (t>>2)*512 + m*64 + (t&3)*16 + (lane & 15);
    int k   = kk*32 + ((lane>>4)<<3) + e;
    float v = w_hh[(((size_t)lay*2 + dir)*G4 + row)*HDIM + k];
    wfrag[a] = tobf(v);
  } else {
    int b = gi - R0 - R1;     // exactly 4096
    bias[b] = b_ih[(size_t)lay*2*G4 + b] + b_hh[(size_t)lay*2*G4 + b];
  }
}

// ---------------- xg = x @ W_ih^T + bias  (M=4096,N=4096,K=1024, bf16 MFMA) ----------------
__global__ __launch_bounds__(256, 1) void gemm_k(const u16* __restrict__ A, const u16* __restrict__ B,
                                                 const float* __restrict__ bias, u16* __restrict__ Cxg){
  __shared__ short alds[128*48];
  __shared__ short blds[128*48];
  int tid = threadIdx.x;
  int row = tid >> 1, hf = tid & 1;
  int w = tid >> 6, l = tid & 63;
  int wr = w >> 1, wc = w & 1;
  int bx = blockIdx.x, by = blockIdx.y;
  const short* Ag = (const short*)A + ((size_t)(by*128 + row))*EDIM + hf*16;
  const short* Bg = (const short*)B + ((size_t)(bx*128 + row))*EDIM + hf*16;
  f32x4 acc[4][4];
  #pragma unroll
  for (int i=0;i<4;i++)
    #pragma unroll
    for (int j=0;j<4;j++) acc[i][j] = (f32x4){0.f,0.f,0.f,0.f};
  for (int kt = 0; kt < 32; ++kt){
    short8 va0 = *(const short8*)(Ag + kt*32);
    short8 va1 = *(const short8*)(Ag + kt*32 + 8);
    short8 vb0 = *(const short8*)(Bg + kt*32);
    short8 vb1 = *(const short8*)(Bg + kt*32 + 8);
    __syncthreads();
    *(short8*)(alds + row*48 + hf*16)     = va0;
    *(short8*)(alds + row*48 + hf*16 + 8) = va1;
    *(short8*)(blds + row*48 + hf*16)     = vb0;
    *(short8*)(blds + row*48 + hf*16 + 8) = vb1;
    __syncthreads();
    short8 af[4], bf[4];
    #pragma unroll
    for (int i=0;i<4;i++) af[i] = *(const short8*)(alds + (wr*64 + i*16 + (l&15))*48 + ((l>>4)<<3));
    #pragma unroll
    for (int j=0;j<4;j++) bf[j] = *(const short8*)(blds + (wc*64 + j*16 + (l&15))*48 + ((l>>4)<<3));
    #pragma unroll
    for (int i=0;i<4;i++)
      #pragma unroll
      for (int j=0;j<4;j++)
        acc[i][j] = __builtin_amdgcn_mfma_f32_16x16x32_bf16(af[i], bf[j], acc[i][j], 0, 0, 0);
  }
  #pragma unroll
  for (int j=0;j<4;j++){
    int col = bx*128 + wc*64 + j*16 + (l & 15);
    float bs = bias[col];
    #pragma unroll
    for (int i=0;i<4;i++){
      int r0 = by*128 + wr*64 + i*16 + ((l>>4)<<2);
      #pragma unroll
      for (int rr=0; rr<4; ++rr){
        float v = acc[i][j][rr] + bs;
        Cxg[(size_t)(r0+rr)*4096 + col] = tobf(v);
      }
    }
  }
}

// ---------------- recurrence: 256 WGs; 8-CU groups formed DYNAMICALLY within one XCD ----------------
// Exchange via shared XCD L2: plain stores (write-through L1) + vmcnt(0) + plain flag store;
// consumers poll flags with sc0 loads (bypass L1, served by shared L2). Fresh ring address per step.
__global__ __launch_bounds__(1024, 4) void recur_k(
    int lay, const u16* __restrict__ xg, const u16* __restrict__ wfrag, u16* ring, u32* flags,
    const float* __restrict__ h0, const float* __restrict__ c0, u16* __restrict__ xout)
{
  __shared__ float glds[256];   // [tile16][row16]
  __shared__ u32 shmeta;
  int tid = threadIdx.x, w = tid >> 6, l = tid & 63;
  if (tid == 0){
    u32 xcc;
    asm volatile("s_getreg_b32 %0, hwreg(HW_REG_XCC_ID)" : "=s"(xcc));
    xcc &= 7u;
    u32* regc = flags + (size_t)(NFLAG_LINES + lay*8 + xcc)*FSTRIDE;
    u32 slot = __hip_atomic_fetch_add(regc, 1u, __ATOMIC_RELAXED, __HIP_MEMORY_SCOPE_AGENT);
    shmeta = (xcc << 8) | (slot & 31u);
  }
  __syncthreads();
  u32 meta = shmeta;
  int m    = (int)(meta & 7u);                                  // member within group
  int gidx = (int)((meta >> 8) & 7u)*4 + (int)((meta >> 3) & 3u); // same-XCD group id 0..31
  int unit = gidx >> 4, grp = gidx & 15;
  int tile = w;

  const u16* wfb = wfrag + ((size_t)((unit*8 + m)*16 + tile))*8192 + l*8;
  short8 afr[16];
  #pragma unroll
  for (int kk=0; kk<16; ++kk) afr[kk] = *(const short8*)(wfb + kk*512);

  u32* flg    = flags + (size_t)((lay*2 + unit)*NGRP + grp)*(8*FSTRIDE);
  u32* myflag = flg + m*FSTRIDE;
  const u32* pollp = flg + (l & 7)*FSTRIDE;
  u16* ringg = ring + ((size_t)(unit*NGRP + grp)*RING_L + (size_t)lay*RING_SLOTS)*HDIM;

  int c = grp;
  int nwarm = (c == 0) ? 0 : WARM;
  int steps = nwarm + CHUNK;
  int base_u = c*CHUNK - nwarm;
  bool upd = (w == 0);
  float cst = 0.0f;
  int budget = 1 << 22;          // latched poll budget: timeout -> visible failure, not hang
  if (upd){
    cst = c0[unit*HDIM + m*64 + l];
    u16 hb = tobf(h0[unit*HDIM + m*64 + l]);
    int oth = __shfl_xor((int)hb, 1);
    if ((l & 1) == 0){
      u32 word = (u32)hb | ((u32)(u16)oth << 16);
      *((u32*)ringg + (m*32 + (l>>1))) = word;          // plain store -> shared XCD L2
    }
    asm volatile("s_waitcnt vmcnt(0)" ::: "memory");
    if (l == 0) *((volatile u32*)myflag) = 1u;
  }

  for (int s = 0; s < steps; ++s){
    int u2 = base_u + s;
    bool real = (u2 >= c*CHUNK);
    int p = unit ? (S_LEN-1-u2) : u2;
    float xgi=0.f, xgf=0.f, xgg=0.f, xgo=0.f;
    if (upd){   // prefetch xg before the poll (independent of h)
      const u16* xp = xg + (size_t)p*4096 + unit*G4 + m*64 + l;
      xgi = frombf(xp[0]); xgf = frombf(xp[512]); xgg = frombf(xp[1024]); xgo = frombf(xp[1536]);
      u32 tgt = (u32)(s + 1);
      u32 v;
      do {
        asm volatile("global_load_dword %0, %1, off sc0\n\t"
                     "s_waitcnt vmcnt(0)"
                     : "=v"(v) : "v"(pollp) : "memory");
      } while (!__all((l >= 8) || (v >= tgt)) && --budget > 0);
    }
    __syncthreads();   // syncA: h(s) visible in L2 for the whole group
    const u16* rs = ringg + (size_t)s*HDIM;
    f32x4 acc0 = (f32x4){0.f,0.f,0.f,0.f};
    f32x4 acc1 = (f32x4){0.f,0.f,0.f,0.f};
    #pragma unroll
    for (int kk=0; kk<16; kk+=2){
      short8 b0 = *(const short8*)(rs + kk*32 + ((l>>4)<<3));
      short8 b1 = *(const short8*)(rs + (kk+1)*32 + ((l>>4)<<3));
      acc0 = __builtin_amdgcn_mfma_f32_16x16x32_bf16(afr[kk],   b0, acc0, 0, 0, 0);
      acc1 = __builtin_amdgcn_mfma_f32_16x16x32_bf16(afr[kk+1], b1, acc1, 0, 0, 0);
    }
    f32x4 acc = acc0 + acc1;
    if ((l & 15) == 0)
      *(f32x4*)(glds + tile*16 + ((l>>4)<<2)) = acc;
    __syncthreads();   // syncB: glds complete
    if (upd){
      int sub = l >> 4, r = l & 15;      // l == sub*16 + r
      float ip = glds[(0*4+sub)*16 + r] + xgi;
      float fp = glds[(1*4+sub)*16 + r] + xgf;
      float gp = glds[(2*4+sub)*16 + r] + xgg;
      float op = glds[(3*4+sub)*16 + r] + xgo;
      float ig = sigmf(ip), fg = sigmf(fp), gv = tanh_fast(gp), og = sigmf(op);
      cst = fg*cst + ig*gv;
      float hv = og * tanh_fast(cst);
      u16 hb = tobf(hv);
      int oth = __shfl_xor((int)hb, 1);
      u16* rs1 = (u16*)rs + HDIM;        // slot s+1
      if ((l & 1) == 0){
        u32 word = (u32)hb | ((u32)(u16)oth << 16);
        *((u32*)rs1 + (m*32 + (l>>1))) = word;          // plain store -> shared XCD L2
      }
      asm volatile("s_waitcnt vmcnt(0)" ::: "memory");   // h in L2 before flag
      if (l == 0) *((volatile u32*)myflag) = (u32)(s + 2);
      if (real)
        xout[(size_t)p*EDIM + unit*HDIM + m*64 + l] = hb; // after flag: off critical path
    }
    // no third barrier: syncA(s+1) orders glds overwrite after wave0's glds reads
  }
}

// ---------------- emission: feats = x3 @ w_out^T + b_out ----------------
__global__ void emis_k(const u16* __restrict__ x3, const float* __restrict__ wout,
                       const float* __restrict__ bout, float* __restrict__ feats){
  int w = threadIdx.x >> 6, l = threadIdx.x & 63;
  int p = blockIdx.x*16 + w;
  const short* xr = (const short*)x3 + (size_t)p*EDIM + l*16;
  short8 xv0 = *(const short8*)(xr);
  short8 xv1 = *(const short8*)(xr + 8);
  float xf[16];
  #pragma unroll
  for (int e=0;e<8;e++){ xf[e] = frombf((u16)xv0[e]); xf[8+e] = frombf((u16)xv1[e]); }
  float accv[5];
  #pragma unroll
  for (int t=0;t<5;t++){
    const float* wr = wout + t*EDIM + l*16;
    float s = 0.f;
    #pragma unroll
    for (int e=0;e<16;e++) s += xf[e]*wr[e];
    accv[t] = s;
  }
  #pragma unroll
  for (int t=0;t<5;t++){
    float s = accv[t];
    #pragma unroll
    for (int d=32; d>=1; d>>=1) s += __shfl_xor(s, d);
    if (l == 0) feats[p*NTAG + t] = s + bout[t];
  }
}

// ---------------- Viterbi forward (sequential, wave-parallel over 25 (next,prev) pairs) ----------------
__global__ __launch_bounds__(64, 1) void vfwd_k(const float* __restrict__ feats, const float* __restrict__ trans,
                                                u32* __restrict__ bp, u32* __restrict__ bestout, float* __restrict__ dout){
  __shared__ float fl[2560];   // 512 steps * 5 tags
  int l = threadIdx.x;
  int n = (l < 25) ? (l / 5) : 0;
  int p = (l < 25) ? (l % 5) : 0;
  float tr = trans[n*5 + p];
  float trEnd = trans[4*5 + p];
  float fv = (p == 3) ? 0.0f : NEGV;
  for (int b2 = 0; b2 < 8; ++b2){
    __syncthreads();
    for (int q = l; q < 2560; q += 64) fl[q] = feats[b2*2560 + q];
    __syncthreads();
    for (int tt = 0; tt < 512; ++tt){
      int t = b2*512 + tt;
      float featv = fl[tt*5 + n];
      float sc = fv + tr;
      float mx = -3.4e38f; int arg = 0;
      #pragma unroll
      for (int k=0;k<5;k++){
        float sk = __shfl(sc, n*5 + k);
        if (sk > mx){ mx = sk; arg = k; }
      }
      float fvnew = mx + featv;
      u32 pk = 0;
      #pragma unroll
      for (int k2=0;k2<5;k2++){
        int a2 = __shfl(arg, k2*5);
        pk |= ((u32)a2 & 7u) << (3*k2);
      }
      if (l == 0) bp[t] = pk;
      fv = __shfl(fvnew, p*5);
    }
  }
  float term = fv + trEnd;  // lanes 0..4 hold p=0..4
  float mx = -3.4e38f; int arg = 0;
  #pragma unroll
  for (int k=0;k<5;k++){
    float tk = __shfl(term, k);
    if (tk > mx){ mx = tk; arg = k; }
  }
  if (l == 0){ dout[0] = mx; bestout[0] = (u32)arg; }
}

// ---------------- backtrack via packed-map suffix composition scan ----------------
__device__ __forceinline__ u32 compose_map(u32 f, u32 g){
  u32 r = 0;
  #pragma unroll
  for (int x=0;x<5;x++){
    u32 gx = (g >> (3*x)) & 7u;
    u32 fx = (f >> (3*gx)) & 7u;
    r |= fx << (3*x);
  }
  return r;
}
__global__ __launch_bounds__(1024) void vback_k(const u32* __restrict__ bp, const u32* __restrict__ best,
                                                float* __restrict__ dout){
  __shared__ u32 A[2][S_LEN];
  int tid = threadIdx.x;
  const u32 IDENT = 18056u;   // 0|1<<3|2<<6|3<<9|4<<12
  #pragma unroll
  for (int r2=0;r2<4;r2++){
    int t = tid + r2*1024;
    A[0][t] = (t < S_LEN-1) ? bp[t+1] : IDENT;
  }
  __syncthreads();
  int cur = 0;
  for (int d=1; d<S_LEN; d<<=1){
    #pragma unroll
    for (int r2=0;r2<4;r2++){
      int t = tid + r2*1024;
      u32 f = A[cur][t];
      u32 res = (t + d < S_LEN) ? compose_map(f, A[cur][t+d]) : f;
      A[cur^1][t] = res;
    }
    __syncthreads();
    cur ^= 1;
  }
  u32 b = best[0] & 7u;
  #pragma unroll
  for (int r2=0;r2<4;r2++){
    int t = tid + r2*1024;
    u32 tag = (A[cur][t] >> (3*b)) & 7u;
    dout[1 + t] = (float)tag;
  }
}

// ---------------- host ----------------
extern "C" void kernel_launch(void* const* d_in, const int* in_sizes, int n_in,
                              void* d_out, int out_size, void* d_ws, size_t ws_size,
                              hipStream_t stream)
{
  const int*   sent = (const int*)d_in[0];
  const float* emb  = (const float*)d_in[1];
  const float* w_ih = (const float*)d_in[2];
  const float* w_hh = (const float*)d_in[3];
  const float* b_ih = (const float*)d_in[4];
  const float* b_hh = (const float*)d_in[5];
  const float* wout = (const float*)d_in[6];
  const float* bout = (const float*)d_in[7];
  const float* trans= (const float*)d_in[8];
  const float* h0   = (const float*)d_in[9];
  const float* c0   = (const float*)d_in[10];
  float* out = (float*)d_out;
  char* ws = (char*)d_ws;
  size_t off = 0;
  auto alloc = [&](size_t bytes)->char*{
    char* pp = ws + off;
    off = (off + bytes + 255) & ~(size_t)255;
    return pp;
  };
  u16* xg     = (u16*)alloc((size_t)S_LEN*4096*2);            // 32 MB  (both dirs)
  u16* xa     = (u16*)alloc((size_t)S_LEN*EDIM*2);            // 8 MB
  u16* xb     = (u16*)alloc((size_t)S_LEN*EDIM*2);            // 8 MB
  u16* wihb   = (u16*)alloc((size_t)2*G4*EDIM*2);             // 8 MB
  u16* wfrag  = (u16*)alloc((size_t)2*G4*HDIM*2);             // 4 MB
  float* bias = (float*)alloc((size_t)2*G4*4);                // 16 KB
  u16* ring   = (u16*)alloc((size_t)2*NGRP*RING_L*HDIM*2);    // ~38 MB (fresh slot per step per layer)
  u32* flags  = (u32*)alloc((size_t)NFLAGS_TOT*4);            // flags + registration counters
  float* feats= (float*)alloc((size_t)S_LEN*NTAG*4);
  u32* bp     = (u32*)alloc((size_t)S_LEN*4);
  u32* best   = (u32*)alloc(256);
  if (off > ws_size) return;  // insufficient workspace -> visible failure

  init_k<<<(NFLAGS_TOT + 255)/256, 256, 0, stream>>>(flags);
  gather_k<<<4096, 256, 0, stream>>>(sent, emb, xa);
  u16* xin = xa; u16* xo = xb;
  for (int l2 = 0; l2 < NLAY; ++l2){
    prep_k<<<24592, 256, 0, stream>>>(l2, w_ih, w_hh, b_ih, b_hh, wihb, wfrag, bias);
    gemm_k<<<dim3(32,32), 256, 0, stream>>>(xin, wihb, bias, xg);
    recur_k<<<256, 1024, 0, stream>>>(l2, xg, wfrag, ring, flags,
                                      h0 + (size_t)l2*2*HDIM, c0 + (size_t)l2*2*HDIM, xo);
    u16* tmp = xin; xin = xo; xo = tmp;
  }
  emis_k<<<256, 1024, 0, stream>>>(xin, wout, bout, feats);
  vfwd_k<<<1, 64, 0, stream>>>(feats, trans, bp, best, out);
  vback_k<<<1, 1024, 0, stream>>>(bp, best, out);
}

// Round 5
// 6978.529 us; speedup vs baseline: 226.6795x; 226.6795x over previous
//
#include <hip/hip_runtime.h>

typedef unsigned int u32;
typedef unsigned short u16;
typedef __attribute__((ext_vector_type(4))) float f32x4;
typedef __attribute__((ext_vector_type(8))) short short8;

#define S_LEN 4096
#define EDIM 1024
#define HDIM 512
#define G4 2048
#define NLAY 3
#define NTAG 5
#define NEGV -10000.0f
#define NGRP 16
#define CHUNK 256
#define WARM 64
#define RING_SLOTS 392
#define RING_L (RING_SLOTS*NLAY)
#define FSTRIDE 16              // u32s per flag (64B line each)
#define NFLAGS (NLAY*2*NGRP*8*FSTRIDE)

__device__ __forceinline__ u16 tobf(float x){
  u32 u = __float_as_uint(x);
  u32 r = (u + 0x7FFFu + ((u >> 16) & 1u)) >> 16;
  return (u16)r;
}
__device__ __forceinline__ float frombf(u16 h){ return __uint_as_float(((u32)h) << 16); }
__device__ __forceinline__ float sigmf(float x){ return 1.0f / (1.0f + __expf(-x)); }
__device__ __forceinline__ float tanh_fast(float x){
  float e = __expf(-2.0f * fabsf(x));
  float t = (1.0f - e) / (1.0f + e);
  return copysignf(t, x);
}

// ---------------- init: zero barrier flags ----------------
__global__ void init_k(u32* flags){
  int i = blockIdx.x*256 + threadIdx.x;
  if (i < NFLAGS) flags[i] = 0u;
}

// ---------------- embedding gather -> bf16 ----------------
__global__ void gather_k(const int* __restrict__ sent, const float* __restrict__ emb, u16* __restrict__ xa){
  int idx = blockIdx.x*256 + threadIdx.x;      // S*E/4 threads
  int p = idx >> 8;
  int k = (idx & 255) << 2;
  int tok = sent[p];
  f32x4 v = *(const f32x4*)(emb + (size_t)tok*EDIM + k);
  u16* o = xa + (size_t)p*EDIM + k;
  o[0]=tobf(v.x); o[1]=tobf(v.y); o[2]=tobf(v.z); o[3]=tobf(v.w);
}

// ---------------- per-layer prep: cast w_ih, repack w_hh MFMA A-frags, bias ----------------
// wfrag flat layout: ((((dir*8+m)*16 + t)*16 + kk)*64 + lane)*8 + e
//   tile t: gate g = t>>2, subband = t&3; row = g*512 + m*64 + (t&3)*16 + (lane&15)
//   k = kk*32 + (lane>>4)*8 + e   (full K=512 per tile, kk in [0,16))
__global__ void prep_k(int lay, const float* __restrict__ w_ih, const float* __restrict__ w_hh,
                       const float* __restrict__ b_ih, const float* __restrict__ b_hh,
                       u16* __restrict__ wihb, u16* __restrict__ wfrag, float* __restrict__ bias){
  int gi = blockIdx.x*256 + threadIdx.x;
  const int R0 = 2*G4*EDIM;   // 4194304
  const int R1 = 2*G4*HDIM;   // 2097152
  if (gi < R0){
    wihb[gi] = tobf(w_ih[(size_t)lay*R0 + gi]);
  } else if (gi < R0 + R1){
    int a = gi - R0;
    int e = a & 7, lane = (a>>3)&63, kk = (a>>9)&15, t = (a>>13)&15, m = (a>>17)&7, dir = (a>>20)&1;
    int row = (t>>2)*512 + m*64 + (t&3)*16 + (lane & 15);
    int k   = kk*32 + ((lane>>4)<<3) + e;
    float v = w_hh[(((size_t)lay*2 + dir)*G4 + row)*HDIM + k];
    wfrag[a] = tobf(v);
  } else {
    int b = gi - R0 - R1;     // exactly 4096
    bias[b] = b_ih[(size_t)lay*2*G4 + b] + b_hh[(size_t)lay*2*G4 + b];
  }
}

// ---------------- xg = x @ W_ih^T + bias  (M=4096,N=4096,K=1024, bf16 MFMA) ----------------
__global__ __launch_bounds__(256, 1) void gemm_k(const u16* __restrict__ A, const u16* __restrict__ B,
                                                 const float* __restrict__ bias, u16* __restrict__ Cxg){
  __shared__ short alds[128*48];
  __shared__ short blds[128*48];
  int tid = threadIdx.x;
  int row = tid >> 1, hf = tid & 1;
  int w = tid >> 6, l = tid & 63;
  int wr = w >> 1, wc = w & 1;
  int bx = blockIdx.x, by = blockIdx.y;
  const short* Ag = (const short*)A + ((size_t)(by*128 + row))*EDIM + hf*16;
  const short* Bg = (const short*)B + ((size_t)(bx*128 + row))*EDIM + hf*16;
  f32x4 acc[4][4];
  #pragma unroll
  for (int i=0;i<4;i++)
    #pragma unroll
    for (int j=0;j<4;j++) acc[i][j] = (f32x4){0.f,0.f,0.f,0.f};
  for (int kt = 0; kt < 32; ++kt){
    short8 va0 = *(const short8*)(Ag + kt*32);
    short8 va1 = *(const short8*)(Ag + kt*32 + 8);
    short8 vb0 = *(const short8*)(Bg + kt*32);
    short8 vb1 = *(const short8*)(Bg + kt*32 + 8);
    __syncthreads();
    *(short8*)(alds + row*48 + hf*16)     = va0;
    *(short8*)(alds + row*48 + hf*16 + 8) = va1;
    *(short8*)(blds + row*48 + hf*16)     = vb0;
    *(short8*)(blds + row*48 + hf*16 + 8) = vb1;
    __syncthreads();
    short8 af[4], bf[4];
    #pragma unroll
    for (int i=0;i<4;i++) af[i] = *(const short8*)(alds + (wr*64 + i*16 + (l&15))*48 + ((l>>4)<<3));
    #pragma unroll
    for (int j=0;j<4;j++) bf[j] = *(const short8*)(blds + (wc*64 + j*16 + (l&15))*48 + ((l>>4)<<3));
    #pragma unroll
    for (int i=0;i<4;i++)
      #pragma unroll
      for (int j=0;j<4;j++)
        acc[i][j] = __builtin_amdgcn_mfma_f32_16x16x32_bf16(af[i], bf[j], acc[i][j], 0, 0, 0);
  }
  #pragma unroll
  for (int j=0;j<4;j++){
    int col = bx*128 + wc*64 + j*16 + (l & 15);
    float bs = bias[col];
    #pragma unroll
    for (int i=0;i<4;i++){
      int r0 = by*128 + wr*64 + i*16 + ((l>>4)<<2);
      #pragma unroll
      for (int rr=0; rr<4; ++rr){
        float v = acc[i][j][rr] + bs;
        Cxg[(size_t)(r0+rr)*4096 + col] = tobf(v);
      }
    }
  }
}

// ---------------- recurrence: 256 WGs; group of 8 CUs per chunk ----------------
// r3-verified mechanism: relaxed agent atomic h-stores -> MALL; explicit vmcnt(0);
// release-store per-CU flag (own 64B line); consumers spin with RELAXED agent loads
// (wave0 lanes 0..7 in parallel) + ONE acquire fence on success.
__global__ __launch_bounds__(1024, 4) void recur_k(
    int lay, const u16* __restrict__ xg, const u16* __restrict__ wfrag, u16* ring, u32* flags,
    const float* __restrict__ h0, const float* __restrict__ c0, u16* __restrict__ xout)
{
  __shared__ float glds[256];   // [tile16][row16]
  int bid = blockIdx.x;
  int xcd = bid & 7, slot = bid >> 3;
  int m = slot & 7, gg = slot >> 3;
  int gidx = xcd*4 + gg;
  int unit = gidx >> 4, grp = gidx & 15;
  int tid = threadIdx.x, w = tid >> 6, l = tid & 63;
  int tile = w;

  const u16* wfb = wfrag + ((size_t)((unit*8 + m)*16 + tile))*8192 + l*8;
  short8 afr[16];
  #pragma unroll
  for (int kk=0; kk<16; ++kk) afr[kk] = *(const short8*)(wfb + kk*512);

  u32* flg    = flags + (size_t)((lay*2 + unit)*NGRP + grp)*(8*FSTRIDE);
  u32* myflag = flg + m*FSTRIDE;
  const u32* pollp = flg + (l & 7)*FSTRIDE;
  u16* ringg = ring + ((size_t)(unit*NGRP + grp)*RING_L + (size_t)lay*RING_SLOTS)*HDIM;

  int c = grp;
  int nwarm = (c == 0) ? 0 : WARM;
  int steps = nwarm + CHUNK;
  int base_u = c*CHUNK - nwarm;
  bool upd = (w == 0);
  float cst = 0.0f;
  if (upd){
    cst = c0[unit*HDIM + m*64 + l];
    u16 hb = tobf(h0[unit*HDIM + m*64 + l]);
    int oth = __shfl_xor((int)hb, 1);
    if ((l & 1) == 0){
      u32 word = (u32)hb | ((u32)(u16)oth << 16);
      __hip_atomic_store((u32*)ringg + (m*32 + (l>>1)), word, __ATOMIC_RELAXED, __HIP_MEMORY_SCOPE_AGENT);
    }
    asm volatile("s_waitcnt vmcnt(0)" ::: "memory");   // wave-level: h0 at MALL before flag
    if (l == 0) __hip_atomic_store(myflag, 1u, __ATOMIC_RELEASE, __HIP_MEMORY_SCOPE_AGENT);
  }

  for (int s = 0; s < steps; ++s){
    int u2 = base_u + s;
    bool real = (u2 >= c*CHUNK);
    int p = unit ? (S_LEN-1-u2) : u2;
    float xgi=0.f, xgf=0.f, xgg=0.f, xgo=0.f;
    if (upd){   // prefetch xg before the poll (independent of h; overlaps flag RTT)
      const u16* xp = xg + (size_t)p*4096 + unit*G4 + m*64 + l;
      xgi = frombf(xp[0]); xgf = frombf(xp[512]); xgg = frombf(xp[1024]); xgo = frombf(xp[1536]);
      u32 tgt = (u32)(s + 1);
      int budget = 1 << 24;    // hang insurance -> visible failure, not timeout
      while (true){
        u32 v = __hip_atomic_load(pollp, __ATOMIC_RELAXED, __HIP_MEMORY_SCOPE_AGENT);
        if (__all((l >= 8) || (v >= tgt))) break;
        if (--budget <= 0) break;
        __builtin_amdgcn_s_sleep(1);
      }
      __builtin_amdgcn_fence(__ATOMIC_ACQUIRE, "agent");  // one invalidate after success
    }
    __syncthreads();   // syncA: h(s) visible for the whole block
    const u16* rs = ringg + (size_t)s*HDIM;
    f32x4 acc0 = (f32x4){0.f,0.f,0.f,0.f};
    f32x4 acc1 = (f32x4){0.f,0.f,0.f,0.f};
    #pragma unroll
    for (int kk=0; kk<16; kk+=2){
      short8 b0 = *(const short8*)(rs + kk*32 + ((l>>4)<<3));
      short8 b1 = *(const short8*)(rs + (kk+1)*32 + ((l>>4)<<3));
      acc0 = __builtin_amdgcn_mfma_f32_16x16x32_bf16(afr[kk],   b0, acc0, 0, 0, 0);
      acc1 = __builtin_amdgcn_mfma_f32_16x16x32_bf16(afr[kk+1], b1, acc1, 0, 0, 0);
    }
    f32x4 acc = acc0 + acc1;
    if ((l & 15) == 0)
      *(f32x4*)(glds + tile*16 + ((l>>4)<<2)) = acc;
    __syncthreads();   // syncB: glds complete
    if (upd){
      int sub = l >> 4, r = l & 15;      // l == sub*16 + r
      float ip = glds[(0*4+sub)*16 + r] + xgi;
      float fp = glds[(1*4+sub)*16 + r] + xgf;
      float gp = glds[(2*4+sub)*16 + r] + xgg;
      float op = glds[(3*4+sub)*16 + r] + xgo;
      float ig = sigmf(ip), fg = sigmf(fp), gv = tanh_fast(gp), og = sigmf(op);
      cst = fg*cst + ig*gv;
      float hv = og * tanh_fast(cst);
      u16 hb = tobf(hv);
      int oth = __shfl_xor((int)hb, 1);
      u16* rs1 = (u16*)rs + HDIM;        // slot s+1
      if ((l & 1) == 0){
        u32 word = (u32)hb | ((u32)(u16)oth << 16);
        __hip_atomic_store((u32*)rs1 + (m*32 + (l>>1)), word, __ATOMIC_RELAXED, __HIP_MEMORY_SCOPE_AGENT);
      }
      asm volatile("s_waitcnt vmcnt(0)" ::: "memory");   // wave-level: h at MALL before flag
      if (l == 0) __hip_atomic_store(myflag, (u32)(s + 2), __ATOMIC_RELEASE, __HIP_MEMORY_SCOPE_AGENT);
      if (real)
        xout[(size_t)p*EDIM + unit*HDIM + m*64 + l] = hb; // after flag: off critical path
    }
    // no third barrier: syncA(s+1) orders next glds writes after wave0's glds reads
  }
}

// ---------------- emission: feats = x3 @ w_out^T + b_out ----------------
__global__ void emis_k(const u16* __restrict__ x3, const float* __restrict__ wout,
                       const float* __restrict__ bout, float* __restrict__ feats){
  int w = threadIdx.x >> 6, l = threadIdx.x & 63;
  int p = blockIdx.x*16 + w;
  const short* xr = (const short*)x3 + (size_t)p*EDIM + l*16;
  short8 xv0 = *(const short8*)(xr);
  short8 xv1 = *(const short8*)(xr + 8);
  float xf[16];
  #pragma unroll
  for (int e=0;e<8;e++){ xf[e] = frombf((u16)xv0[e]); xf[8+e] = frombf((u16)xv1[e]); }
  float accv[5];
  #pragma unroll
  for (int t=0;t<5;t++){
    const float* wr = wout + t*EDIM + l*16;
    float s = 0.f;
    #pragma unroll
    for (int e=0;e<16;e++) s += xf[e]*wr[e];
    accv[t] = s;
  }
  #pragma unroll
  for (int t=0;t<5;t++){
    float s = accv[t];
    #pragma unroll
    for (int d=32; d>=1; d>>=1) s += __shfl_xor(s, d);
    if (l == 0) feats[p*NTAG + t] = s + bout[t];
  }
}

// ---------------- Viterbi forward (sequential, wave-parallel over 25 (next,prev) pairs) ----------------
__global__ __launch_bounds__(64, 1) void vfwd_k(const float* __restrict__ feats, const float* __restrict__ trans,
                                                u32* __restrict__ bp, u32* __restrict__ bestout, float* __restrict__ dout){
  __shared__ float fl[2560];   // 512 steps * 5 tags
  int l = threadIdx.x;
  int n = (l < 25) ? (l / 5) : 0;
  int p = (l < 25) ? (l % 5) : 0;
  float tr = trans[n*5 + p];
  float trEnd = trans[4*5 + p];
  float fv = (p == 3) ? 0.0f : NEGV;
  for (int b2 = 0; b2 < 8; ++b2){
    __syncthreads();
    for (int q = l; q < 2560; q += 64) fl[q] = feats[b2*2560 + q];
    __syncthreads();
    for (int tt = 0; tt < 512; ++tt){
      int t = b2*512 + tt;
      float featv = fl[tt*5 + n];
      float sc = fv + tr;
      float mx = -3.4e38f; int arg = 0;
      #pragma unroll
      for (int k=0;k<5;k++){
        float sk = __shfl(sc, n*5 + k);
        if (sk > mx){ mx = sk; arg = k; }
      }
      float fvnew = mx + featv;
      u32 pk = 0;
      #pragma unroll
      for (int k2=0;k2<5;k2++){
        int a2 = __shfl(arg, k2*5);
        pk |= ((u32)a2 & 7u) << (3*k2);
      }
      if (l == 0) bp[t] = pk;
      fv = __shfl(fvnew, p*5);
    }
  }
  float term = fv + trEnd;  // lanes 0..4 hold p=0..4
  float mx = -3.4e38f; int arg = 0;
  #pragma unroll
  for (int k=0;k<5;k++){
    float tk = __shfl(term, k);
    if (tk > mx){ mx = tk; arg = k; }
  }
  if (l == 0){ dout[0] = mx; bestout[0] = (u32)arg; }
}

// ---------------- backtrack via packed-map suffix composition scan ----------------
__device__ __forceinline__ u32 compose_map(u32 f, u32 g){
  u32 r = 0;
  #pragma unroll
  for (int x=0;x<5;x++){
    u32 gx = (g >> (3*x)) & 7u;
    u32 fx = (f >> (3*gx)) & 7u;
    r |= fx << (3*x);
  }
  return r;
}
__global__ __launch_bounds__(1024) void vback_k(const u32* __restrict__ bp, const u32* __restrict__ best,
                                                float* __restrict__ dout){
  __shared__ u32 A[2][S_LEN];
  int tid = threadIdx.x;
  const u32 IDENT = 18056u;   // 0|1<<3|2<<6|3<<9|4<<12
  #pragma unroll
  for (int r2=0;r2<4;r2++){
    int t = tid + r2*1024;
    A[0][t] = (t < S_LEN-1) ? bp[t+1] : IDENT;
  }
  __syncthreads();
  int cur = 0;
  for (int d=1; d<S_LEN; d<<=1){
    #pragma unroll
    for (int r2=0;r2<4;r2++){
      int t = tid + r2*1024;
      u32 f = A[cur][t];
      u32 res = (t + d < S_LEN) ? compose_map(f, A[cur][t+d]) : f;
      A[cur^1][t] = res;
    }
    __syncthreads();
    cur ^= 1;
  }
  u32 b = best[0] & 7u;
  #pragma unroll
  for (int r2=0;r2<4;r2++){
    int t = tid + r2*1024;
    u32 tag = (A[cur][t] >> (3*b)) & 7u;
    dout[1 + t] = (float)tag;
  }
}

// ---------------- host ----------------
extern "C" void kernel_launch(void* const* d_in, const int* in_sizes, int n_in,
                              void* d_out, int out_size, void* d_ws, size_t ws_size,
                              hipStream_t stream)
{
  const int*   sent = (const int*)d_in[0];
  const float* emb  = (const float*)d_in[1];
  const float* w_ih = (const float*)d_in[2];
  const float* w_hh = (const float*)d_in[3];
  const float* b_ih = (const float*)d_in[4];
  const float* b_hh = (const float*)d_in[5];
  const float* wout = (const float*)d_in[6];
  const float* bout = (const float*)d_in[7];
  const float* trans= (const float*)d_in[8];
  const float* h0   = (const float*)d_in[9];
  const float* c0   = (const float*)d_in[10];
  float* out = (float*)d_out;
  char* ws = (char*)d_ws;
  size_t off = 0;
  auto alloc = [&](size_t bytes)->char*{
    char* pp = ws + off;
    off = (off + bytes + 255) & ~(size_t)255;
    return pp;
  };
  u16* xg     = (u16*)alloc((size_t)S_LEN*4096*2);            // 32 MB  (both dirs)
  u16* xa     = (u16*)alloc((size_t)S_LEN*EDIM*2);            // 8 MB
  u16* xb     = (u16*)alloc((size_t)S_LEN*EDIM*2);            // 8 MB
  u16* wihb   = (u16*)alloc((size_t)2*G4*EDIM*2);             // 8 MB
  u16* wfrag  = (u16*)alloc((size_t)2*G4*HDIM*2);             // 4 MB
  float* bias = (float*)alloc((size_t)2*G4*4);                // 16 KB
  u16* ring   = (u16*)alloc((size_t)2*NGRP*RING_L*HDIM*2);    // ~38 MB (fresh slot per step per layer)
  u32* flags  = (u32*)alloc((size_t)NFLAGS*4);                // one 64B line per CU-flag
  float* feats= (float*)alloc((size_t)S_LEN*NTAG*4);
  u32* bp     = (u32*)alloc((size_t)S_LEN*4);
  u32* best   = (u32*)alloc(256);
  if (off > ws_size) return;  // insufficient workspace -> visible failure

  init_k<<<(NFLAGS + 255)/256, 256, 0, stream>>>(flags);
  gather_k<<<4096, 256, 0, stream>>>(sent, emb, xa);
  u16* xin = xa; u16* xo = xb;
  for (int l2 = 0; l2 < NLAY; ++l2){
    prep_k<<<24592, 256, 0, stream>>>(l2, w_ih, w_hh, b_ih, b_hh, wihb, wfrag, bias);
    gemm_k<<<dim3(32,32), 256, 0, stream>>>(xin, wihb, bias, xg);
    recur_k<<<256, 1024, 0, stream>>>(l2, xg, wfrag, ring, flags,
                                      h0 + (size_t)l2*2*HDIM, c0 + (size_t)l2*2*HDIM, xo);
    u16* tmp = xin; xin = xo; xo = tmp;
  }
  emis_k<<<256, 1024, 0, stream>>>(xin, wout, bout, feats);
  vfwd_k<<<1, 64, 0, stream>>>(feats, trans, bp, best, out);
  vback_k<<<1, 1024, 0, stream>>>(bp, best, out);
}